// Round 1
// baseline (3804.685 us; speedup 1.0000x reference)
//
#include <hip/hip_runtime.h>
#include <math.h>

#define V_N 100000
#define C_N 420000
#define E_N 1260000
#define L_N 3

__device__ __forceinline__ float fsig(float x) {
    return 1.0f / (1.0f + __expf(-x));
}
__device__ __forceinline__ float ftanh(float x) {
    x = fminf(fmaxf(x, -15.0f), 15.0f);
    float t = __expf(2.0f * x);
    return (t - 1.0f) / (t + 1.0f);
}

// ---------------------------------------------------------------------------
// Precompute W' = wih @ W2  (stored transposed [64][9]) and c2 = wih @ b2 [9]
// for both directions and all 3 layers.  prep slot s = side*3 + l, 585 floats.
// ---------------------------------------------------------------------------
__global__ void k_prep(const float* __restrict__ v2c_w2, const float* __restrict__ v2c_b2,
                       const float* __restrict__ c2v_w2, const float* __restrict__ c2v_b2,
                       const float* __restrict__ cls_wih, const float* __restrict__ var_wih,
                       float* __restrict__ prep) {
    const int per = 576 + 9;
    int t = blockIdx.x * blockDim.x + threadIdx.x;
    if (t >= 6 * per) return;
    int s = t / per;
    int r = t % per;
    int side = s / 3;   // 0: v2c->cls, 1: c2v->var
    int l = s % 3;
    const float* wih = (side == 0 ? cls_wih : var_wih) + l * 9 * 64;
    const float* W2  = (side == 0 ? v2c_w2 : c2v_w2) + l * 64 * 64;
    const float* b2  = (side == 0 ? v2c_b2 : c2v_b2) + l * 64;
    float* out = prep + s * per;
    if (r < 576) {
        int j = r / 9, k = r % 9;
        float acc = 0.0f;
        for (int o = 0; o < 64; ++o) acc += wih[k * 64 + o] * W2[o * 64 + j];
        out[j * 9 + k] = acc;           // WpT[j][k]
    } else {
        int k = r - 576;
        float acc = 0.0f;
        for (int o = 0; o < 64; ++o) acc += wih[k * 64 + o] * b2[o];
        out[576 + k] = acc;             // c2[k]
    }
}

// ---------------------------------------------------------------------------
// Attention logits per clause + per-block max partials.
// ---------------------------------------------------------------------------
__global__ __launch_bounds__(256) void k_att(const float* __restrict__ cf,
                                             const float* __restrict__ aw1,
                                             const float* __restrict__ ab1,
                                             const float* __restrict__ aw2,
                                             const float* __restrict__ ab2,
                                             float* __restrict__ logits,
                                             float* __restrict__ pmax) {
    int c = blockIdx.x * blockDim.x + threadIdx.x;
    float logit = -1e30f;
    if (c < C_N) {
        float h0 = cf[c * 3], h1 = cf[c * 3 + 1], h2 = cf[c * 3 + 2];
        float acc = ab2[0];
        #pragma unroll
        for (int k = 0; k < 64; ++k) {
            float tv = ftanh(aw1[k * 3] * h0 + aw1[k * 3 + 1] * h1 +
                             aw1[k * 3 + 2] * h2 + ab1[k]);
            acc += aw2[k] * tv;
        }
        logits[c] = acc;
        logit = acc;
    }
    float m = logit;
    #pragma unroll
    for (int off = 32; off; off >>= 1) m = fmaxf(m, __shfl_xor(m, off));
    __shared__ float smax[4];
    int lane = threadIdx.x & 63, wid = threadIdx.x >> 6;
    if (lane == 0) smax[wid] = m;
    __syncthreads();
    if (threadIdx.x == 0) {
        float mm = fmaxf(fmaxf(smax[0], smax[1]), fmaxf(smax[2], smax[3]));
        pmax[blockIdx.x] = mm;
    }
}

// ---------------------------------------------------------------------------
// Global softmax: every block redundantly reduces pmax -> gmax, then partial
// sums exp(logit - gmax) -> atomic S.  Block 0 stores gmax.
// ---------------------------------------------------------------------------
__global__ __launch_bounds__(256) void k_sum(const float* __restrict__ logits,
                                             const float* __restrict__ pmax, int npmax,
                                             float* __restrict__ S, float* __restrict__ gmax) {
    float m = -1e30f;
    for (int i = threadIdx.x; i < npmax; i += blockDim.x) m = fmaxf(m, pmax[i]);
    #pragma unroll
    for (int off = 32; off; off >>= 1) m = fmaxf(m, __shfl_xor(m, off));
    __shared__ float sm[4];
    int lane = threadIdx.x & 63, wid = threadIdx.x >> 6;
    if (lane == 0) sm[wid] = m;
    __syncthreads();
    float mm = fmaxf(fmaxf(sm[0], sm[1]), fmaxf(sm[2], sm[3]));

    int c = blockIdx.x * blockDim.x + threadIdx.x;
    float e = 0.0f;
    if (c < C_N) e = __expf(logits[c] - mm);
    float s = e;
    #pragma unroll
    for (int off = 32; off; off >>= 1) s += __shfl_xor(s, off);
    __shared__ float ss[4];
    if (lane == 0) ss[wid] = s;
    __syncthreads();
    if (threadIdx.x == 0) {
        unsafeAtomicAdd(S, ss[0] + ss[1] + ss[2] + ss[3]);
        if (blockIdx.x == 0) *gmax = mm;
    }
}

// ---------------------------------------------------------------------------
// Fused edge MLP + (optional attention scale) + 9-float scatter-add.
// One thread per edge.  h1 = relu(W1 x + b1) (64), u = W'T h1 + c2 (9).
// ---------------------------------------------------------------------------
template <bool ATT>
__global__ __launch_bounds__(256) void k_edge(const float* __restrict__ feat,
                                              const float* __restrict__ ef,
                                              const int* __restrict__ gidx,
                                              const int* __restrict__ sidx,
                                              const float* __restrict__ w1,
                                              const float* __restrict__ b1,
                                              const float* __restrict__ prep,
                                              const float* __restrict__ logits,
                                              const float* __restrict__ gmaxp,
                                              const float* __restrict__ Sp,
                                              float* __restrict__ gsum) {
    int e = blockIdx.x * blockDim.x + threadIdx.x;
    if (e >= E_N) return;
    int g = gidx[e], sc = sidx[e];
    float x0 = feat[g * 3], x1 = feat[g * 3 + 1], x2 = feat[g * 3 + 2];
    float2 efv = *(const float2*)(ef + 2 * (size_t)e);
    float x3 = efv.x, x4 = efv.y;

    float u[9];
    #pragma unroll
    for (int k = 0; k < 9; ++k) u[k] = prep[576 + k];
    #pragma unroll
    for (int j = 0; j < 64; ++j) {
        float h = w1[j * 5] * x0 + w1[j * 5 + 1] * x1 + w1[j * 5 + 2] * x2 +
                  w1[j * 5 + 3] * x3 + w1[j * 5 + 4] * x4 + b1[j];
        h = fmaxf(h, 0.0f);
        #pragma unroll
        for (int k = 0; k < 9; ++k) u[k] += prep[j * 9 + k] * h;
    }
    float scale = 1.0f;
    if (ATT) scale = __expf(logits[sc] - gmaxp[0]) / Sp[0];
    #pragma unroll
    for (int k = 0; k < 9; ++k)
        unsafeAtomicAdd(&gsum[(size_t)sc * 9 + k], scale * u[k]);
}

// ---------------------------------------------------------------------------
// GRU update: gi = gsum + bih (message path already folded), gh = whh h + bhh.
// ---------------------------------------------------------------------------
__global__ __launch_bounds__(256) void k_gru(const float* __restrict__ gsum,
                                             const float* __restrict__ hin,
                                             const float* __restrict__ whh,
                                             const float* __restrict__ bih,
                                             const float* __restrict__ bhh,
                                             float* __restrict__ hout, int N) {
    int i = blockIdx.x * blockDim.x + threadIdx.x;
    if (i >= N) return;
    float h0 = hin[i * 3], h1 = hin[i * 3 + 1], h2 = hin[i * 3 + 2];
    float gi[9], gh[9];
    #pragma unroll
    for (int k = 0; k < 9; ++k) gi[k] = gsum[(size_t)i * 9 + k] + bih[k];
    #pragma unroll
    for (int k = 0; k < 9; ++k)
        gh[k] = whh[k * 3] * h0 + whh[k * 3 + 1] * h1 + whh[k * 3 + 2] * h2 + bhh[k];
    float r0 = fsig(gi[0] + gh[0]), r1 = fsig(gi[1] + gh[1]), r2 = fsig(gi[2] + gh[2]);
    float z0 = fsig(gi[3] + gh[3]), z1 = fsig(gi[4] + gh[4]), z2 = fsig(gi[5] + gh[5]);
    float n0 = ftanh(gi[6] + r0 * gh[6]);
    float n1 = ftanh(gi[7] + r1 * gh[7]);
    float n2 = ftanh(gi[8] + r2 * gh[8]);
    hout[i * 3 + 0] = (1.0f - z0) * n0 + z0 * h0;
    hout[i * 3 + 1] = (1.0f - z1) * n1 + z1 * h1;
    hout[i * 3 + 2] = (1.0f - z2) * n2 + z2 * h2;
}

extern "C" void kernel_launch(void* const* d_in, const int* in_sizes, int n_in,
                              void* d_out, int out_size, void* d_ws, size_t ws_size,
                              hipStream_t stream) {
    const float* vf0     = (const float*)d_in[0];
    const float* cf0     = (const float*)d_in[1];
    const float* ef      = (const float*)d_in[2];
    const float* v2c_w1  = (const float*)d_in[3];
    const float* v2c_b1  = (const float*)d_in[4];
    const float* v2c_w2  = (const float*)d_in[5];
    const float* v2c_b2  = (const float*)d_in[6];
    const float* c2v_w1  = (const float*)d_in[7];
    const float* c2v_b1  = (const float*)d_in[8];
    const float* c2v_w2  = (const float*)d_in[9];
    const float* c2v_b2  = (const float*)d_in[10];
    const float* var_wih = (const float*)d_in[11];
    const float* var_whh = (const float*)d_in[12];
    const float* var_bih = (const float*)d_in[13];
    const float* var_bhh = (const float*)d_in[14];
    const float* cls_wih = (const float*)d_in[15];
    const float* cls_whh = (const float*)d_in[16];
    const float* cls_bih = (const float*)d_in[17];
    const float* cls_bhh = (const float*)d_in[18];
    const float* att_w1  = (const float*)d_in[19];
    const float* att_b1  = (const float*)d_in[20];
    const float* att_w2  = (const float*)d_in[21];
    const float* att_b2  = (const float*)d_in[22];
    const int*   var_idx = (const int*)d_in[23];
    const int*   cls_idx = (const int*)d_in[24];
    float* dout = (float*)d_out;

    // ---- workspace layout (floats) ----
    float* ws = (float*)d_ws;
    float* gsumC  = ws;                                   // C*9
    float* gsumV  = gsumC + (size_t)C_N * 9;              // V*9
    float* Sbuf   = gsumV + (size_t)V_N * 9;              // 1 (zeroed with gsum)
    float* gmax   = Sbuf + 64;                            // 1
    float* logits = gmax + 64;                            // C
    float* pmax   = logits + C_N;                         // nAttBlk
    const int nAttBlk = (C_N + 255) / 256;
    float* prep   = pmax + ((nAttBlk + 63) / 64) * 64;    // 6*585
    float* vfA    = prep + 6 * (576 + 9) + 58;            // V*3 (pad to align)
    float* vfB    = vfA + (size_t)V_N * 3;
    float* cfA    = vfB + (size_t)V_N * 3;
    float* cfB    = cfA + (size_t)C_N * 3;

    const size_t zero_bytes = ((size_t)C_N * 9 + (size_t)V_N * 9 + 1) * 4;

    k_prep<<<14, 256, 0, stream>>>(v2c_w2, v2c_b2, c2v_w2, c2v_b2,
                                   cls_wih, var_wih, prep);

    const float* vf_cur = vf0;
    const float* cf_cur = cf0;
    const int nEBlk = (E_N + 255) / 256;
    const int nVBlk = (V_N + 255) / 256;

    for (int l = 0; l < L_N; ++l) {
        float* vf_next = (l == 0) ? vfA : (l == 1) ? vfB : dout;
        float* cf_next = (l == 0) ? cfA : (l == 1) ? cfB : (dout + (size_t)V_N * 3);

        hipMemsetAsync(gsumC, 0, zero_bytes, stream);

        k_att<<<nAttBlk, 256, 0, stream>>>(cf_cur,
                                           att_w1 + l * 192, att_b1 + l * 64,
                                           att_w2 + l * 64, att_b2 + l,
                                           logits, pmax);
        k_sum<<<nAttBlk, 256, 0, stream>>>(logits, pmax, nAttBlk, Sbuf, gmax);

        // var -> clause (attention-weighted)
        k_edge<true><<<nEBlk, 256, 0, stream>>>(vf_cur, ef, var_idx, cls_idx,
                                                v2c_w1 + l * 320, v2c_b1 + l * 64,
                                                prep + (0 * 3 + l) * 585,
                                                logits, gmax, Sbuf, gsumC);
        // clause -> var (uses OLD clause features)
        k_edge<false><<<nEBlk, 256, 0, stream>>>(cf_cur, ef, cls_idx, var_idx,
                                                 c2v_w1 + l * 320, c2v_b1 + l * 64,
                                                 prep + (1 * 3 + l) * 585,
                                                 logits, gmax, Sbuf, gsumV);

        k_gru<<<nAttBlk, 256, 0, stream>>>(gsumC, cf_cur,
                                           cls_whh + l * 27, cls_bih + l * 9,
                                           cls_bhh + l * 9, cf_next, C_N);
        k_gru<<<nVBlk, 256, 0, stream>>>(gsumV, vf_cur,
                                         var_whh + l * 27, var_bih + l * 9,
                                         var_bhh + l * 9, vf_next, V_N);

        vf_cur = vf_next;
        cf_cur = cf_next;
    }
}

// Round 4
// 984.513 us; speedup vs baseline: 3.8645x; 3.8645x over previous
//
#include <hip/hip_runtime.h>
#include <hip/hip_fp16.h>
#include <math.h>

#define V_N 100000
#define C_N 420000
#define E_N 1260000
#define L_N 3

__device__ __forceinline__ float fsig(float x) {
    return 1.0f / (1.0f + __expf(-x));
}
__device__ __forceinline__ float ftanh(float x) {
    x = fminf(fmaxf(x, -15.0f), 15.0f);
    float t = __expf(2.0f * x);
    return (t - 1.0f) / (t + 1.0f);
}

// ---------------------------------------------------------------------------
// Consolidated per-(side,layer) weight block, stride 1040 floats:
//   [j*16 + 0..4]  = w1 row j (5)      [j*16 + 5] = b1[j]
//   [j*16 + 6..14] = wp[j][k] = sum_o wih[k][o]*W2[o][j]   [j*16+15] = pad
//   [1024 + k]     = c2[k] = sum_o wih[k][o]*b2[o]
// side 0: v2c (into clauses, cls_wih);  side 1: c2v (into vars, var_wih)
// ---------------------------------------------------------------------------
__global__ void k_prep(const float* __restrict__ v2c_w1, const float* __restrict__ v2c_b1,
                       const float* __restrict__ v2c_w2, const float* __restrict__ v2c_b2,
                       const float* __restrict__ c2v_w1, const float* __restrict__ c2v_b1,
                       const float* __restrict__ c2v_w2, const float* __restrict__ c2v_b2,
                       const float* __restrict__ cls_wih, const float* __restrict__ var_wih,
                       float* __restrict__ prep) {
    int t = blockIdx.x * blockDim.x + threadIdx.x;
    if (t >= 6 * 1040) return;
    int s = t / 1040, r = t % 1040;
    int side = s / 3, l = s % 3;
    const float* w1  = (side ? c2v_w1 : v2c_w1) + l * 320;
    const float* b1  = (side ? c2v_b1 : v2c_b1) + l * 64;
    const float* W2  = (side ? c2v_w2 : v2c_w2) + l * 4096;
    const float* b2  = (side ? c2v_b2 : v2c_b2) + l * 64;
    const float* wih = (side ? var_wih : cls_wih) + l * 576;
    float v = 0.0f;
    if (r < 1024) {
        int j = r >> 4, q = r & 15;
        if (q < 5) v = w1[j * 5 + q];
        else if (q == 5) v = b1[j];
        else if (q < 15) {
            int k = q - 6; float a = 0.0f;
            for (int o = 0; o < 64; ++o) a += wih[k * 64 + o] * W2[o * 64 + j];
            v = a;
        }
    } else if (r < 1033) {
        int k = r - 1024; float a = 0.0f;
        for (int o = 0; o < 64; ++o) a += wih[k * 64 + o] * b2[o];
        v = a;
    }
    prep[t] = v;
}

// ---------------------------------------------------------------------------
// CSR build: count, 2-level exclusive scan, fill (inverse permutation).
// ---------------------------------------------------------------------------
__global__ __launch_bounds__(256) void k_count(const int* __restrict__ ci, const int* __restrict__ vi,
                                               int* __restrict__ cntC, int* __restrict__ cntV) {
    int e = blockIdx.x * 256 + threadIdx.x;
    if (e >= E_N) return;
    atomicAdd(&cntC[ci[e]], 1);
    atomicAdd(&cntV[vi[e]], 1);
}

__global__ __launch_bounds__(256) void k_scan1(const int* __restrict__ cnt, int N,
                                               int* __restrict__ bsum) {
    int b = blockIdx.x, t = threadIdx.x;
    int base = b * 1024 + t * 4;
    int s = 0;
    #pragma unroll
    for (int q = 0; q < 4; ++q) { int i = base + q; if (i < N) s += cnt[i]; }
    __shared__ int sh[256];
    sh[t] = s; __syncthreads();
    for (int d = 128; d; d >>= 1) { if (t < d) sh[t] += sh[t + d]; __syncthreads(); }
    if (t == 0) bsum[b] = sh[0];
}

__global__ __launch_bounds__(512) void k_scan2(int* __restrict__ bsum, int nb,
                                               int* __restrict__ rowN) {
    __shared__ int sh[512];
    int t = threadIdx.x;
    int v = (t < nb) ? bsum[t] : 0;
    sh[t] = v; __syncthreads();
    for (int d = 1; d < 512; d <<= 1) {
        int add = (t >= d) ? sh[t - d] : 0;
        __syncthreads();
        sh[t] += add;
        __syncthreads();
    }
    if (t < nb) bsum[t] = sh[t] - v;       // exclusive block offsets
    if (t == nb - 1) *rowN = sh[t];        // total
}

__global__ __launch_bounds__(256) void k_scan3(const int* __restrict__ cnt, int N,
                                               const int* __restrict__ bsum,
                                               int* __restrict__ row, int* __restrict__ curs) {
    int b = blockIdx.x, t = threadIdx.x;
    int base = b * 1024 + t * 4;
    int v[4], local[4];
    #pragma unroll
    for (int q = 0; q < 4; ++q) { int i = base + q; v[q] = (i < N) ? cnt[i] : 0; }
    local[0] = 0; local[1] = v[0]; local[2] = v[0] + v[1]; local[3] = v[0] + v[1] + v[2];
    int mysum = local[3] + v[3];
    __shared__ int sh[256];
    sh[t] = mysum; __syncthreads();
    for (int d = 1; d < 256; d <<= 1) {
        int add = (t >= d) ? sh[t - d] : 0;
        __syncthreads();
        sh[t] += add;
        __syncthreads();
    }
    int excl = sh[t] - mysum + bsum[b];
    #pragma unroll
    for (int q = 0; q < 4; ++q) {
        int i = base + q;
        if (i < N) { int p = excl + local[q]; row[i] = p; curs[i] = p; }
    }
}

__global__ __launch_bounds__(256) void k_fill(const int* __restrict__ ci, const int* __restrict__ vi,
                                              int* __restrict__ cursC, int* __restrict__ cursV,
                                              int* __restrict__ invC, int* __restrict__ invV) {
    int e = blockIdx.x * 256 + threadIdx.x;
    if (e >= E_N) return;
    invC[e] = atomicAdd(&cursC[ci[e]], 1);
    invV[e] = atomicAdd(&cursV[vi[e]], 1);
}

// ---------------------------------------------------------------------------
// Attention logits + block max partials.
// ---------------------------------------------------------------------------
__global__ __launch_bounds__(256) void k_att(const float* __restrict__ cf,
                                             const float* __restrict__ aw1,
                                             const float* __restrict__ ab1,
                                             const float* __restrict__ aw2,
                                             const float* __restrict__ ab2,
                                             float* __restrict__ logits,
                                             float* __restrict__ pmax) {
    int c = blockIdx.x * blockDim.x + threadIdx.x;
    float logit = -1e30f;
    if (c < C_N) {
        float h0 = cf[c * 3], h1 = cf[c * 3 + 1], h2 = cf[c * 3 + 2];
        float acc = ab2[0];
        #pragma unroll
        for (int k = 0; k < 64; ++k) {
            float tv = ftanh(aw1[k * 3] * h0 + aw1[k * 3 + 1] * h1 +
                             aw1[k * 3 + 2] * h2 + ab1[k]);
            acc += aw2[k] * tv;
        }
        logits[c] = acc;
        logit = acc;
    }
    float m = logit;
    #pragma unroll
    for (int off = 32; off; off >>= 1) m = fmaxf(m, __shfl_xor(m, off));
    __shared__ float smax[4];
    int lane = threadIdx.x & 63, wid = threadIdx.x >> 6;
    if (lane == 0) smax[wid] = m;
    __syncthreads();
    if (threadIdx.x == 0)
        pmax[blockIdx.x] = fmaxf(fmaxf(smax[0], smax[1]), fmaxf(smax[2], smax[3]));
}

// Partial exp-sums (each block redundantly reduces pmax to the global max).
__global__ __launch_bounds__(256) void k_sum(const float* __restrict__ logits,
                                             const float* __restrict__ pmax, int npmax,
                                             float* __restrict__ Spart) {
    __shared__ float sh[4];
    float m = -1e30f;
    for (int i = threadIdx.x; i < npmax; i += 256) m = fmaxf(m, pmax[i]);
    #pragma unroll
    for (int off = 32; off; off >>= 1) m = fmaxf(m, __shfl_xor(m, off));
    int lane = threadIdx.x & 63, wid = threadIdx.x >> 6;
    if (lane == 0) sh[wid] = m;
    __syncthreads();
    float mm = fmaxf(fmaxf(sh[0], sh[1]), fmaxf(sh[2], sh[3]));
    __syncthreads();
    int c = blockIdx.x * 256 + threadIdx.x;
    float e = (c < C_N) ? __expf(logits[c] - mm) : 0.0f;
    #pragma unroll
    for (int off = 32; off; off >>= 1) e += __shfl_xor(e, off);
    if (lane == 0) sh[wid] = e;
    __syncthreads();
    if (threadIdx.x == 0) Spart[blockIdx.x] = sh[0] + sh[1] + sh[2] + sh[3];
}

// Final: Sg[0] = sum(Spart), Sg[1] = gmax.
__global__ __launch_bounds__(256) void k_red(const float* __restrict__ Spart,
                                             const float* __restrict__ pmax, int n,
                                             float* __restrict__ Sg) {
    __shared__ float sh[8];
    float s = 0.0f, m = -1e30f;
    for (int i = threadIdx.x; i < n; i += 256) { s += Spart[i]; m = fmaxf(m, pmax[i]); }
    #pragma unroll
    for (int off = 32; off; off >>= 1) { s += __shfl_xor(s, off); m = fmaxf(m, __shfl_xor(m, off)); }
    int lane = threadIdx.x & 63, wid = threadIdx.x >> 6;
    if (lane == 0) { sh[wid] = s; sh[4 + wid] = m; }
    __syncthreads();
    if (threadIdx.x == 0) {
        Sg[0] = sh[0] + sh[1] + sh[2] + sh[3];
        Sg[1] = fmaxf(fmaxf(sh[4], sh[5]), fmaxf(sh[6], sh[7]));
    }
}

// ---------------------------------------------------------------------------
// Edge MLP (folded to 9 outputs), written fp16 at CSR slot inv[e] (no atomics).
// ---------------------------------------------------------------------------
__global__ __launch_bounds__(256) void k_edge(const float* __restrict__ feat,
                                              const float* __restrict__ ef,
                                              const int* __restrict__ gidx,
                                              const int* __restrict__ inv,
                                              const float* __restrict__ prep,
                                              uint2* __restrict__ umsg) {
    __shared__ float W[1040];
    for (int i = threadIdx.x; i < 1040; i += 256) W[i] = prep[i];
    __syncthreads();
    int e = blockIdx.x * 256 + threadIdx.x;
    if (e >= E_N) return;
    int g = gidx[e];
    float x0 = feat[g * 3], x1 = feat[g * 3 + 1], x2 = feat[g * 3 + 2];
    float2 efv = *(const float2*)(ef + 2 * (size_t)e);
    float u[9];
    #pragma unroll
    for (int k = 0; k < 9; ++k) u[k] = 0.0f;
    for (int j = 0; j < 64; ++j) {
        const float* wj = &W[j * 16];
        float h = wj[0] * x0 + wj[1] * x1 + wj[2] * x2 + wj[3] * efv.x + wj[4] * efv.y + wj[5];
        h = fmaxf(h, 0.0f);
        #pragma unroll
        for (int k = 0; k < 9; ++k) u[k] += wj[6 + k] * h;
    }
    union { __half h[12]; uint2 q[3]; } pk;
    #pragma unroll
    for (int k = 0; k < 9; ++k) pk.h[k] = __float2half(u[k]);
    pk.h[9] = pk.h[10] = pk.h[11] = __float2half(0.0f);
    size_t pos = (size_t)inv[e] * 3;
    umsg[pos] = pk.q[0]; umsg[pos + 1] = pk.q[1]; umsg[pos + 2] = pk.q[2];
}

// ---------------------------------------------------------------------------
// Fused gather + (attention scale) + c2 fold + GRU.  One thread per node.
// ---------------------------------------------------------------------------
template <bool ATT>
__global__ __launch_bounds__(256) void k_node(const uint2* __restrict__ umsg,
                                              const int* __restrict__ row,
                                              const float* __restrict__ hin,
                                              const float* __restrict__ logits,
                                              const float* __restrict__ Sg,
                                              const float* __restrict__ c2,
                                              const float* __restrict__ whh,
                                              const float* __restrict__ bih,
                                              const float* __restrict__ bhh,
                                              float* __restrict__ hout, int N) {
    int i = blockIdx.x * 256 + threadIdx.x;
    if (i >= N) return;
    int p0 = row[i], p1 = row[i + 1];
    float u[9];
    #pragma unroll
    for (int k = 0; k < 9; ++k) u[k] = 0.0f;
    for (int p = p0; p < p1; ++p) {
        union { __half h[12]; uint2 q[3]; } pk;
        const uint2* r = umsg + (size_t)p * 3;
        pk.q[0] = r[0]; pk.q[1] = r[1]; pk.q[2] = r[2];
        #pragma unroll
        for (int k = 0; k < 9; ++k) u[k] += __half2float(pk.h[k]);
    }
    float cnt = (float)(p1 - p0);
    float scale = 1.0f;
    if (ATT) scale = __expf(logits[i] - Sg[1]) / Sg[0];
    float h0 = hin[i * 3], h1 = hin[i * 3 + 1], h2 = hin[i * 3 + 2];
    float gi[9], gh[9];
    #pragma unroll
    for (int k = 0; k < 9; ++k) gi[k] = scale * (u[k] + cnt * c2[k]) + bih[k];
    #pragma unroll
    for (int k = 0; k < 9; ++k)
        gh[k] = whh[k * 3] * h0 + whh[k * 3 + 1] * h1 + whh[k * 3 + 2] * h2 + bhh[k];
    float r0 = fsig(gi[0] + gh[0]), r1 = fsig(gi[1] + gh[1]), r2 = fsig(gi[2] + gh[2]);
    float z0 = fsig(gi[3] + gh[3]), z1 = fsig(gi[4] + gh[4]), z2 = fsig(gi[5] + gh[5]);
    float n0 = ftanh(gi[6] + r0 * gh[6]);
    float n1 = ftanh(gi[7] + r1 * gh[7]);
    float n2 = ftanh(gi[8] + r2 * gh[8]);
    hout[i * 3 + 0] = (1.0f - z0) * n0 + z0 * h0;
    hout[i * 3 + 1] = (1.0f - z1) * n1 + z1 * h1;
    hout[i * 3 + 2] = (1.0f - z2) * n2 + z2 * h2;
}

extern "C" void kernel_launch(void* const* d_in, const int* in_sizes, int n_in,
                              void* d_out, int out_size, void* d_ws, size_t ws_size,
                              hipStream_t stream) {
    const float* vf0     = (const float*)d_in[0];
    const float* cf0     = (const float*)d_in[1];
    const float* ef      = (const float*)d_in[2];
    const float* v2c_w1  = (const float*)d_in[3];
    const float* v2c_b1  = (const float*)d_in[4];
    const float* v2c_w2  = (const float*)d_in[5];
    const float* v2c_b2  = (const float*)d_in[6];
    const float* c2v_w1  = (const float*)d_in[7];
    const float* c2v_b1  = (const float*)d_in[8];
    const float* c2v_w2  = (const float*)d_in[9];
    const float* c2v_b2  = (const float*)d_in[10];
    const float* var_wih = (const float*)d_in[11];
    const float* var_whh = (const float*)d_in[12];
    const float* var_bih = (const float*)d_in[13];
    const float* var_bhh = (const float*)d_in[14];
    const float* cls_wih = (const float*)d_in[15];
    const float* cls_whh = (const float*)d_in[16];
    const float* cls_bih = (const float*)d_in[17];
    const float* cls_bhh = (const float*)d_in[18];
    const float* att_w1  = (const float*)d_in[19];
    const float* att_b1  = (const float*)d_in[20];
    const float* att_w2  = (const float*)d_in[21];
    const float* att_b2  = (const float*)d_in[22];
    const int*   var_idx = (const int*)d_in[23];
    const int*   cls_idx = (const int*)d_in[24];
    float* dout = (float*)d_out;

    // ---- workspace layout ----
    char* w = (char*)d_ws;
    auto alloc = [&](size_t bytes) { char* p = w; w += (bytes + 255) & ~(size_t)255; return p; };
    int*   rowC   = (int*)alloc((C_N + 1) * 4);
    int*   rowV   = (int*)alloc((V_N + 1) * 4);
    int*   cursC  = (int*)alloc((size_t)C_N * 4);   // doubles as count buffer
    int*   cursV  = (int*)alloc((size_t)V_N * 4);
    int*   invC   = (int*)alloc((size_t)E_N * 4);
    int*   invV   = (int*)alloc((size_t)E_N * 4);
    int*   bsum   = (int*)alloc(512 * 4);
    float* logits = (float*)alloc((size_t)C_N * 4);
    float* pmax   = (float*)alloc(2048 * 4);
    float* Spart  = (float*)alloc(2048 * 4);
    float* Sg     = (float*)alloc(2 * 4);
    float* prep   = (float*)alloc(6 * 1040 * 4);
    uint2* umsg   = (uint2*)alloc((size_t)E_N * 3 * 8);
    float* vfA    = (float*)alloc((size_t)V_N * 3 * 4);
    float* vfB    = (float*)alloc((size_t)V_N * 3 * 4);
    float* cfA    = (float*)alloc((size_t)C_N * 3 * 4);
    float* cfB    = (float*)alloc((size_t)C_N * 3 * 4);

    const int nE = (E_N + 255) / 256;
    const int nC = (C_N + 255) / 256;     // 1641, also att/pmax block count
    const int nV = (V_N + 255) / 256;
    const int nbC = (C_N + 1023) / 1024;  // 411
    const int nbV = (V_N + 1023) / 1024;  // 98

    k_prep<<<(6 * 1040 + 255) / 256, 256, 0, stream>>>(
        v2c_w1, v2c_b1, v2c_w2, v2c_b2, c2v_w1, c2v_b1, c2v_w2, c2v_b2,
        cls_wih, var_wih, prep);

    hipMemsetAsync(cursC, 0, (size_t)C_N * 4, stream);
    hipMemsetAsync(cursV, 0, (size_t)V_N * 4, stream);
    k_count<<<nE, 256, 0, stream>>>(cls_idx, var_idx, cursC, cursV);
    k_scan1<<<nbC, 256, 0, stream>>>(cursC, C_N, bsum);
    k_scan2<<<1, 512, 0, stream>>>(bsum, nbC, rowC + C_N);
    k_scan3<<<nbC, 256, 0, stream>>>(cursC, C_N, bsum, rowC, cursC);
    k_scan1<<<nbV, 256, 0, stream>>>(cursV, V_N, bsum);
    k_scan2<<<1, 512, 0, stream>>>(bsum, nbV, rowV + V_N);
    k_scan3<<<nbV, 256, 0, stream>>>(cursV, V_N, bsum, rowV, cursV);
    k_fill<<<nE, 256, 0, stream>>>(cls_idx, var_idx, cursC, cursV, invC, invV);

    const float* vf_cur = vf0;
    const float* cf_cur = cf0;
    for (int l = 0; l < L_N; ++l) {
        float* vf_next = (l == 0) ? vfA : (l == 1) ? vfB : dout;
        float* cf_next = (l == 0) ? cfA : (l == 1) ? cfB : (dout + (size_t)V_N * 3);

        k_att<<<nC, 256, 0, stream>>>(cf_cur, att_w1 + l * 192, att_b1 + l * 64,
                                      att_w2 + l * 64, att_b2 + l, logits, pmax);
        k_sum<<<nC, 256, 0, stream>>>(logits, pmax, nC, Spart);
        k_red<<<1, 256, 0, stream>>>(Spart, pmax, nC, Sg);

        // var -> clause messages into clause-CSR order
        k_edge<<<nE, 256, 0, stream>>>(vf_cur, ef, var_idx, invC,
                                       prep + (0 * 3 + l) * 1040, umsg);
        k_node<true><<<nC, 256, 0, stream>>>(umsg, rowC, cf_cur, logits, Sg,
                                             prep + (0 * 3 + l) * 1040 + 1024,
                                             cls_whh + l * 27, cls_bih + l * 9,
                                             cls_bhh + l * 9, cf_next, C_N);

        // clause -> var messages (OLD clause features) into var-CSR order
        k_edge<<<nE, 256, 0, stream>>>(cf_cur, ef, cls_idx, invV,
                                       prep + (1 * 3 + l) * 1040, umsg);
        k_node<false><<<nV, 256, 0, stream>>>(umsg, rowV, vf_cur, logits, Sg,
                                              prep + (1 * 3 + l) * 1040 + 1024,
                                              var_whh + l * 27, var_bih + l * 9,
                                              var_bhh + l * 9, vf_next, V_N);

        vf_cur = vf_next;
        cf_cur = cf_next;
    }
}

// Round 5
// 926.674 us; speedup vs baseline: 4.1057x; 1.0624x over previous
//
#include <hip/hip_runtime.h>
#include <hip/hip_fp16.h>
#include <math.h>

#define V_N 100000
#define C_N 420000
#define E_N 1260000
#define L_N 3

__device__ __forceinline__ float fsig(float x) {
    return 1.0f / (1.0f + __expf(-x));
}
__device__ __forceinline__ float ftanh(float x) {
    x = fminf(fmaxf(x, -15.0f), 15.0f);
    float t = __expf(2.0f * x);
    return (t - 1.0f) / (t + 1.0f);
}

// ---------------------------------------------------------------------------
// Consolidated per-(side,layer) weight block, stride 1040 floats:
//   [j*16 + 0..4]  = w1 row j (5)      [j*16 + 5] = b1[j]
//   [j*16 + 6..14] = wp[j][k] = sum_o wih[k][o]*W2[o][j]   [j*16+15] = pad
//   [1024 + k]     = c2[k] = sum_o wih[k][o]*b2[o]
// ---------------------------------------------------------------------------
__global__ void k_prep(const float* __restrict__ v2c_w1, const float* __restrict__ v2c_b1,
                       const float* __restrict__ v2c_w2, const float* __restrict__ v2c_b2,
                       const float* __restrict__ c2v_w1, const float* __restrict__ c2v_b1,
                       const float* __restrict__ c2v_w2, const float* __restrict__ c2v_b2,
                       const float* __restrict__ cls_wih, const float* __restrict__ var_wih,
                       float* __restrict__ prep) {
    int t = blockIdx.x * blockDim.x + threadIdx.x;
    if (t >= 6 * 1040) return;
    int s = t / 1040, r = t % 1040;
    int side = s / 3, l = s % 3;
    const float* w1  = (side ? c2v_w1 : v2c_w1) + l * 320;
    const float* b1  = (side ? c2v_b1 : v2c_b1) + l * 64;
    const float* W2  = (side ? c2v_w2 : v2c_w2) + l * 4096;
    const float* b2  = (side ? c2v_b2 : v2c_b2) + l * 64;
    const float* wih = (side ? var_wih : cls_wih) + l * 576;
    float v = 0.0f;
    if (r < 1024) {
        int j = r >> 4, q = r & 15;
        if (q < 5) v = w1[j * 5 + q];
        else if (q == 5) v = b1[j];
        else if (q < 15) {
            int k = q - 6; float a = 0.0f;
            for (int o = 0; o < 64; ++o) a += wih[k * 64 + o] * W2[o * 64 + j];
            v = a;
        }
    } else if (r < 1033) {
        int k = r - 1024; float a = 0.0f;
        for (int o = 0; o < 64; ++o) a += wih[k * 64 + o] * b2[o];
        v = a;
    }
    prep[t] = v;
}

// ---------------------------------------------------------------------------
// Histogram + rank in ONE atomic pass: rank[e] = old count (position of e
// among edges with the same destination).  The second atomic pass (k_fill)
// is eliminated: inv[e] = row[dest] + rank[e] computed inline in k_edge.
// ---------------------------------------------------------------------------
__global__ __launch_bounds__(256) void k_countrank(const int* __restrict__ ci,
                                                   const int* __restrict__ vi,
                                                   int* __restrict__ cntC, int* __restrict__ cntV,
                                                   int* __restrict__ rankC, int* __restrict__ rankV) {
    int e = blockIdx.x * 256 + threadIdx.x;
    if (e >= E_N) return;
    rankC[e] = atomicAdd(&cntC[ci[e]], 1);
    rankV[e] = atomicAdd(&cntV[vi[e]], 1);
}

// Dual-side block sums: blocks [0,nbC) -> C, [nbC,nbC+nbV) -> V.
__global__ __launch_bounds__(256) void k_scanA(const int* __restrict__ cntC,
                                               const int* __restrict__ cntV, int nbC,
                                               int* __restrict__ bsumC, int* __restrict__ bsumV) {
    int b = blockIdx.x, t = threadIdx.x;
    const int* cnt; int N; int* bs; int bb;
    if (b < nbC) { cnt = cntC; N = C_N; bs = bsumC; bb = b; }
    else         { cnt = cntV; N = V_N; bs = bsumV; bb = b - nbC; }
    int base = bb * 1024 + t * 4;
    int s = 0;
    #pragma unroll
    for (int q = 0; q < 4; ++q) { int i = base + q; if (i < N) s += cnt[i]; }
    __shared__ int sh[256];
    sh[t] = s; __syncthreads();
    for (int d = 128; d; d >>= 1) { if (t < d) sh[t] += sh[t + d]; __syncthreads(); }
    if (t == 0) bs[bb] = sh[0];
}

// Exclusive scan of the block sums; block 0 -> C, block 1 -> V.
__global__ __launch_bounds__(512) void k_scanB(int* __restrict__ bsumC, int nbC, int* __restrict__ totC,
                                               int* __restrict__ bsumV, int nbV, int* __restrict__ totV) {
    int* bsum = blockIdx.x ? bsumV : bsumC;
    int nb    = blockIdx.x ? nbV : nbC;
    int* tot  = blockIdx.x ? totV : totC;
    __shared__ int sh[512];
    int t = threadIdx.x;
    int v = (t < nb) ? bsum[t] : 0;
    sh[t] = v; __syncthreads();
    for (int d = 1; d < 512; d <<= 1) {
        int add = (t >= d) ? sh[t - d] : 0;
        __syncthreads();
        sh[t] += add;
        __syncthreads();
    }
    if (t < nb) bsum[t] = sh[t] - v;
    if (t == nb - 1) *tot = sh[t];
}

// Dual-side: row offsets from local exclusive scan + block offset.
__global__ __launch_bounds__(256) void k_scanC(const int* __restrict__ cntC,
                                               const int* __restrict__ cntV, int nbC,
                                               const int* __restrict__ bsumC,
                                               const int* __restrict__ bsumV,
                                               int* __restrict__ rowC, int* __restrict__ rowV) {
    int b = blockIdx.x, t = threadIdx.x;
    const int* cnt; int N; const int* bs; int* row; int bb;
    if (b < nbC) { cnt = cntC; N = C_N; bs = bsumC; row = rowC; bb = b; }
    else         { cnt = cntV; N = V_N; bs = bsumV; row = rowV; bb = b - nbC; }
    int base = bb * 1024 + t * 4;
    int v[4], local[4];
    #pragma unroll
    for (int q = 0; q < 4; ++q) { int i = base + q; v[q] = (i < N) ? cnt[i] : 0; }
    local[0] = 0; local[1] = v[0]; local[2] = v[0] + v[1]; local[3] = v[0] + v[1] + v[2];
    int mysum = local[3] + v[3];
    __shared__ int sh[256];
    sh[t] = mysum; __syncthreads();
    for (int d = 1; d < 256; d <<= 1) {
        int add = (t >= d) ? sh[t - d] : 0;
        __syncthreads();
        sh[t] += add;
        __syncthreads();
    }
    int excl = sh[t] - mysum + bs[bb];
    #pragma unroll
    for (int q = 0; q < 4; ++q) {
        int i = base + q;
        if (i < N) row[i] = excl + local[q];
    }
}

// ---------------------------------------------------------------------------
// Attention logits + block max partials.  Block 0 also zeroes Sg[0] for the
// atomic exp-sum in k_sum (stream order guarantees it lands first).
// ---------------------------------------------------------------------------
__global__ __launch_bounds__(256) void k_att(const float* __restrict__ cf,
                                             const float* __restrict__ aw1,
                                             const float* __restrict__ ab1,
                                             const float* __restrict__ aw2,
                                             const float* __restrict__ ab2,
                                             float* __restrict__ logits,
                                             float* __restrict__ pmax,
                                             float* __restrict__ Sg) {
    if (blockIdx.x == 0 && threadIdx.x == 0) Sg[0] = 0.0f;
    int c = blockIdx.x * blockDim.x + threadIdx.x;
    float logit = -1e30f;
    if (c < C_N) {
        float h0 = cf[c * 3], h1 = cf[c * 3 + 1], h2 = cf[c * 3 + 2];
        float acc = ab2[0];
        #pragma unroll
        for (int k = 0; k < 64; ++k) {
            float tv = ftanh(aw1[k * 3] * h0 + aw1[k * 3 + 1] * h1 +
                             aw1[k * 3 + 2] * h2 + ab1[k]);
            acc += aw2[k] * tv;
        }
        logits[c] = acc;
        logit = acc;
    }
    float m = logit;
    #pragma unroll
    for (int off = 32; off; off >>= 1) m = fmaxf(m, __shfl_xor(m, off));
    __shared__ float smax[4];
    int lane = threadIdx.x & 63, wid = threadIdx.x >> 6;
    if (lane == 0) smax[wid] = m;
    __syncthreads();
    if (threadIdx.x == 0)
        pmax[blockIdx.x] = fmaxf(fmaxf(smax[0], smax[1]), fmaxf(smax[2], smax[3]));
}

// Exp partial sums -> atomic Sg[0]; block 0 stores gmax in Sg[1].
__global__ __launch_bounds__(256) void k_sum(const float* __restrict__ logits,
                                             const float* __restrict__ pmax, int npmax,
                                             float* __restrict__ Sg) {
    __shared__ float sh[4];
    float m = -1e30f;
    for (int i = threadIdx.x; i < npmax; i += 256) m = fmaxf(m, pmax[i]);
    #pragma unroll
    for (int off = 32; off; off >>= 1) m = fmaxf(m, __shfl_xor(m, off));
    int lane = threadIdx.x & 63, wid = threadIdx.x >> 6;
    if (lane == 0) sh[wid] = m;
    __syncthreads();
    float mm = fmaxf(fmaxf(sh[0], sh[1]), fmaxf(sh[2], sh[3]));
    __syncthreads();
    int c = blockIdx.x * 256 + threadIdx.x;
    float e = (c < C_N) ? __expf(logits[c] - mm) : 0.0f;
    #pragma unroll
    for (int off = 32; off; off >>= 1) e += __shfl_xor(e, off);
    if (lane == 0) sh[wid] = e;
    __syncthreads();
    if (threadIdx.x == 0) {
        unsafeAtomicAdd(&Sg[0], sh[0] + sh[1] + sh[2] + sh[3]);
        if (blockIdx.x == 0) Sg[1] = mm;
    }
}

// ---------------------------------------------------------------------------
// Edge MLP (folded to 9 outputs); slot computed inline: row[dest]+rank[e].
// The row gather (2 MB table, L2-resident) hides under the 64x15 FMA loop.
// ---------------------------------------------------------------------------
__global__ __launch_bounds__(256) void k_edge(const float* __restrict__ feat,
                                              const float* __restrict__ ef,
                                              const int* __restrict__ gidx,
                                              const int* __restrict__ didx,
                                              const int* __restrict__ row,
                                              const int* __restrict__ rank,
                                              const float* __restrict__ prep,
                                              uint2* __restrict__ umsg) {
    __shared__ float W[1040];
    for (int i = threadIdx.x; i < 1040; i += 256) W[i] = prep[i];
    __syncthreads();
    int e = blockIdx.x * 256 + threadIdx.x;
    if (e >= E_N) return;
    int g = gidx[e];
    int pos = row[didx[e]] + rank[e];
    float x0 = feat[g * 3], x1 = feat[g * 3 + 1], x2 = feat[g * 3 + 2];
    float2 efv = *(const float2*)(ef + 2 * (size_t)e);
    float u[9];
    #pragma unroll
    for (int k = 0; k < 9; ++k) u[k] = 0.0f;
    for (int j = 0; j < 64; ++j) {
        const float* wj = &W[j * 16];
        float h = wj[0] * x0 + wj[1] * x1 + wj[2] * x2 + wj[3] * efv.x + wj[4] * efv.y + wj[5];
        h = fmaxf(h, 0.0f);
        #pragma unroll
        for (int k = 0; k < 9; ++k) u[k] += wj[6 + k] * h;
    }
    union { __half h[12]; uint2 q[3]; } pk;
    #pragma unroll
    for (int k = 0; k < 9; ++k) pk.h[k] = __float2half(u[k]);
    pk.h[9] = pk.h[10] = pk.h[11] = __float2half(0.0f);
    size_t p = (size_t)pos * 3;
    umsg[p] = pk.q[0]; umsg[p + 1] = pk.q[1]; umsg[p + 2] = pk.q[2];
}

// ---------------------------------------------------------------------------
// Fused gather + (attention scale) + c2 fold + GRU.  One thread per node.
// ---------------------------------------------------------------------------
template <bool ATT>
__global__ __launch_bounds__(256) void k_node(const uint2* __restrict__ umsg,
                                              const int* __restrict__ row,
                                              const float* __restrict__ hin,
                                              const float* __restrict__ logits,
                                              const float* __restrict__ Sg,
                                              const float* __restrict__ c2,
                                              const float* __restrict__ whh,
                                              const float* __restrict__ bih,
                                              const float* __restrict__ bhh,
                                              float* __restrict__ hout, int N) {
    int i = blockIdx.x * 256 + threadIdx.x;
    if (i >= N) return;
    int p0 = row[i], p1 = row[i + 1];
    float u[9];
    #pragma unroll
    for (int k = 0; k < 9; ++k) u[k] = 0.0f;
    for (int p = p0; p < p1; ++p) {
        union { __half h[12]; uint2 q[3]; } pk;
        const uint2* r = umsg + (size_t)p * 3;
        pk.q[0] = r[0]; pk.q[1] = r[1]; pk.q[2] = r[2];
        #pragma unroll
        for (int k = 0; k < 9; ++k) u[k] += __half2float(pk.h[k]);
    }
    float cnt = (float)(p1 - p0);
    float scale = 1.0f;
    if (ATT) scale = __expf(logits[i] - Sg[1]) / Sg[0];
    float h0 = hin[i * 3], h1 = hin[i * 3 + 1], h2 = hin[i * 3 + 2];
    float gi[9], gh[9];
    #pragma unroll
    for (int k = 0; k < 9; ++k) gi[k] = scale * (u[k] + cnt * c2[k]) + bih[k];
    #pragma unroll
    for (int k = 0; k < 9; ++k)
        gh[k] = whh[k * 3] * h0 + whh[k * 3 + 1] * h1 + whh[k * 3 + 2] * h2 + bhh[k];
    float r0 = fsig(gi[0] + gh[0]), r1 = fsig(gi[1] + gh[1]), r2 = fsig(gi[2] + gh[2]);
    float z0 = fsig(gi[3] + gh[3]), z1 = fsig(gi[4] + gh[4]), z2 = fsig(gi[5] + gh[5]);
    float n0 = ftanh(gi[6] + r0 * gh[6]);
    float n1 = ftanh(gi[7] + r1 * gh[7]);
    float n2 = ftanh(gi[8] + r2 * gh[8]);
    hout[i * 3 + 0] = (1.0f - z0) * n0 + z0 * h0;
    hout[i * 3 + 1] = (1.0f - z1) * n1 + z1 * h1;
    hout[i * 3 + 2] = (1.0f - z2) * n2 + z2 * h2;
}

extern "C" void kernel_launch(void* const* d_in, const int* in_sizes, int n_in,
                              void* d_out, int out_size, void* d_ws, size_t ws_size,
                              hipStream_t stream) {
    const float* vf0     = (const float*)d_in[0];
    const float* cf0     = (const float*)d_in[1];
    const float* ef      = (const float*)d_in[2];
    const float* v2c_w1  = (const float*)d_in[3];
    const float* v2c_b1  = (const float*)d_in[4];
    const float* v2c_w2  = (const float*)d_in[5];
    const float* v2c_b2  = (const float*)d_in[6];
    const float* c2v_w1  = (const float*)d_in[7];
    const float* c2v_b1  = (const float*)d_in[8];
    const float* c2v_w2  = (const float*)d_in[9];
    const float* c2v_b2  = (const float*)d_in[10];
    const float* var_wih = (const float*)d_in[11];
    const float* var_whh = (const float*)d_in[12];
    const float* var_bih = (const float*)d_in[13];
    const float* var_bhh = (const float*)d_in[14];
    const float* cls_wih = (const float*)d_in[15];
    const float* cls_whh = (const float*)d_in[16];
    const float* cls_bih = (const float*)d_in[17];
    const float* cls_bhh = (const float*)d_in[18];
    const float* att_w1  = (const float*)d_in[19];
    const float* att_b1  = (const float*)d_in[20];
    const float* att_w2  = (const float*)d_in[21];
    const float* att_b2  = (const float*)d_in[22];
    const int*   var_idx = (const int*)d_in[23];
    const int*   cls_idx = (const int*)d_in[24];
    float* dout = (float*)d_out;

    // ---- workspace layout ----
    char* w = (char*)d_ws;
    auto alloc = [&](size_t bytes) { char* p = w; w += (bytes + 255) & ~(size_t)255; return p; };
    int*   rowC   = (int*)alloc((C_N + 1) * 4);
    int*   rowV   = (int*)alloc((V_N + 1) * 4);
    int*   cntC   = (int*)alloc((size_t)C_N * 4);   // cntC/cntV adjacent: single memset
    int*   cntV   = (int*)alloc((size_t)V_N * 4);
    char*  cntEnd = w;
    int*   rankC  = (int*)alloc((size_t)E_N * 4);
    int*   rankV  = (int*)alloc((size_t)E_N * 4);
    int*   bsumC  = (int*)alloc(512 * 4);
    int*   bsumV  = (int*)alloc(512 * 4);
    float* logits = (float*)alloc((size_t)C_N * 4);
    float* pmax   = (float*)alloc(2048 * 4);
    float* Sg     = (float*)alloc(64 * 4);
    float* prep   = (float*)alloc(6 * 1040 * 4);
    uint2* umsg   = (uint2*)alloc((size_t)E_N * 3 * 8);
    float* vfA    = (float*)alloc((size_t)V_N * 3 * 4);
    float* vfB    = (float*)alloc((size_t)V_N * 3 * 4);
    float* cfA    = (float*)alloc((size_t)C_N * 3 * 4);
    float* cfB    = (float*)alloc((size_t)C_N * 3 * 4);

    const int nE  = (E_N + 255) / 256;
    const int nC  = (C_N + 255) / 256;     // 1641
    const int nV  = (V_N + 255) / 256;
    const int nbC = (C_N + 1023) / 1024;   // 411
    const int nbV = (V_N + 1023) / 1024;   // 98

    k_prep<<<(6 * 1040 + 255) / 256, 256, 0, stream>>>(
        v2c_w1, v2c_b1, v2c_w2, v2c_b2, c2v_w1, c2v_b1, c2v_w2, c2v_b2,
        cls_wih, var_wih, prep);

    hipMemsetAsync(cntC, 0, (size_t)(cntEnd - (char*)cntC), stream);
    k_countrank<<<nE, 256, 0, stream>>>(cls_idx, var_idx, cntC, cntV, rankC, rankV);
    k_scanA<<<nbC + nbV, 256, 0, stream>>>(cntC, cntV, nbC, bsumC, bsumV);
    k_scanB<<<2, 512, 0, stream>>>(bsumC, nbC, rowC + C_N, bsumV, nbV, rowV + V_N);
    k_scanC<<<nbC + nbV, 256, 0, stream>>>(cntC, cntV, nbC, bsumC, bsumV, rowC, rowV);

    const float* vf_cur = vf0;
    const float* cf_cur = cf0;
    for (int l = 0; l < L_N; ++l) {
        float* vf_next = (l == 0) ? vfA : (l == 1) ? vfB : dout;
        float* cf_next = (l == 0) ? cfA : (l == 1) ? cfB : (dout + (size_t)V_N * 3);

        k_att<<<nC, 256, 0, stream>>>(cf_cur, att_w1 + l * 192, att_b1 + l * 64,
                                      att_w2 + l * 64, att_b2 + l, logits, pmax, Sg);
        k_sum<<<nC, 256, 0, stream>>>(logits, pmax, nC, Sg);

        // var -> clause messages into clause-CSR order
        k_edge<<<nE, 256, 0, stream>>>(vf_cur, ef, var_idx, cls_idx, rowC, rankC,
                                       prep + (0 * 3 + l) * 1040, umsg);
        k_node<true><<<nC, 256, 0, stream>>>(umsg, rowC, cf_cur, logits, Sg,
                                             prep + (0 * 3 + l) * 1040 + 1024,
                                             cls_whh + l * 27, cls_bih + l * 9,
                                             cls_bhh + l * 9, cf_next, C_N);

        // clause -> var messages (OLD clause features) into var-CSR order
        k_edge<<<nE, 256, 0, stream>>>(cf_cur, ef, cls_idx, var_idx, rowV, rankV,
                                       prep + (1 * 3 + l) * 1040, umsg);
        k_node<false><<<nV, 256, 0, stream>>>(umsg, rowV, vf_cur, logits, Sg,
                                              prep + (1 * 3 + l) * 1040 + 1024,
                                              var_whh + l * 27, var_bih + l * 9,
                                              var_bhh + l * 9, vf_next, V_N);

        vf_cur = vf_next;
        cf_cur = cf_next;
    }
}

// Round 6
// 806.330 us; speedup vs baseline: 4.7185x; 1.1492x over previous
//
#include <hip/hip_runtime.h>
#include <hip/hip_fp16.h>
#include <math.h>

#define V_N 100000
#define C_N 420000
#define E_N 1260000
#define L_N 3
#define NCBLK 1641   // ceil(C_N/256)
#define NVBLK 391    // ceil(V_N/256)
#define NEBLK 4922   // ceil(E_N/256)

__device__ __forceinline__ float fsig(float x) {
    return 1.0f / (1.0f + __expf(-x));
}
__device__ __forceinline__ float ftanh(float x) {
    x = fminf(fmaxf(x, -15.0f), 15.0f);
    float t = __expf(2.0f * x);
    return (t - 1.0f) / (t + 1.0f);
}

// ---------------------------------------------------------------------------
// Consolidated per-(side,layer) weight block, stride 1040 floats:
//   [j*16 + 0..4]  = w1 row j (5)      [j*16 + 5] = b1[j]
//   [j*16 + 6..14] = wp[j][k] = sum_o wih[k][o]*W2[o][j]   [j*16+15] = pad
//   [1024 + k]     = c2[k] = sum_o wih[k][o]*b2[o]
// ---------------------------------------------------------------------------
__global__ void k_prep(const float* __restrict__ v2c_w1, const float* __restrict__ v2c_b1,
                       const float* __restrict__ v2c_w2, const float* __restrict__ v2c_b2,
                       const float* __restrict__ c2v_w1, const float* __restrict__ c2v_b1,
                       const float* __restrict__ c2v_w2, const float* __restrict__ c2v_b2,
                       const float* __restrict__ cls_wih, const float* __restrict__ var_wih,
                       float* __restrict__ prep) {
    int t = blockIdx.x * blockDim.x + threadIdx.x;
    if (t >= 6 * 1040) return;
    int s = t / 1040, r = t % 1040;
    int side = s / 3, l = s % 3;
    const float* w1  = (side ? c2v_w1 : v2c_w1) + l * 320;
    const float* b1  = (side ? c2v_b1 : v2c_b1) + l * 64;
    const float* W2  = (side ? c2v_w2 : v2c_w2) + l * 4096;
    const float* b2  = (side ? c2v_b2 : v2c_b2) + l * 64;
    const float* wih = (side ? var_wih : cls_wih) + l * 576;
    float v = 0.0f;
    if (r < 1024) {
        int j = r >> 4, q = r & 15;
        if (q < 5) v = w1[j * 5 + q];
        else if (q == 5) v = b1[j];
        else if (q < 15) {
            int k = q - 6; float a = 0.0f;
            for (int o = 0; o < 64; ++o) a += wih[k * 64 + o] * W2[o * 64 + j];
            v = a;
        }
    } else if (r < 1033) {
        int k = r - 1024; float a = 0.0f;
        for (int o = 0; o < 64; ++o) a += wih[k * 64 + o] * b2[o];
        v = a;
    }
    prep[t] = v;
}

// ---------------------------------------------------------------------------
// Histogram + rank in ONE atomic pass (rank = old count).
// ---------------------------------------------------------------------------
__global__ __launch_bounds__(256) void k_countrank(const int* __restrict__ ci,
                                                   const int* __restrict__ vi,
                                                   int* __restrict__ cntC, int* __restrict__ cntV,
                                                   int* __restrict__ rankC, int* __restrict__ rankV) {
    int e = blockIdx.x * 256 + threadIdx.x;
    if (e >= E_N) return;
    rankC[e] = atomicAdd(&cntC[ci[e]], 1);
    rankV[e] = atomicAdd(&cntV[vi[e]], 1);
}

// Dual-side block sums: blocks [0,nbC) -> C, [nbC,nbC+nbV) -> V.
__global__ __launch_bounds__(256) void k_scanA(const int* __restrict__ cntC,
                                               const int* __restrict__ cntV, int nbC,
                                               int* __restrict__ bsumC, int* __restrict__ bsumV) {
    int b = blockIdx.x, t = threadIdx.x;
    const int* cnt; int N; int* bs; int bb;
    if (b < nbC) { cnt = cntC; N = C_N; bs = bsumC; bb = b; }
    else         { cnt = cntV; N = V_N; bs = bsumV; bb = b - nbC; }
    int base = bb * 1024 + t * 4;
    int s = 0;
    #pragma unroll
    for (int q = 0; q < 4; ++q) { int i = base + q; if (i < N) s += cnt[i]; }
    __shared__ int sh[256];
    sh[t] = s; __syncthreads();
    for (int d = 128; d; d >>= 1) { if (t < d) sh[t] += sh[t + d]; __syncthreads(); }
    if (t == 0) bs[bb] = sh[0];
}

__global__ __launch_bounds__(512) void k_scanB(int* __restrict__ bsumC, int nbC, int* __restrict__ totC,
                                               int* __restrict__ bsumV, int nbV, int* __restrict__ totV) {
    int* bsum = blockIdx.x ? bsumV : bsumC;
    int nb    = blockIdx.x ? nbV : nbC;
    int* tot  = blockIdx.x ? totV : totC;
    __shared__ int sh[512];
    int t = threadIdx.x;
    int v = (t < nb) ? bsum[t] : 0;
    sh[t] = v; __syncthreads();
    for (int d = 1; d < 512; d <<= 1) {
        int add = (t >= d) ? sh[t - d] : 0;
        __syncthreads();
        sh[t] += add;
        __syncthreads();
    }
    if (t < nb) bsum[t] = sh[t] - v;
    if (t == nb - 1) *tot = sh[t];
}

__global__ __launch_bounds__(256) void k_scanC(const int* __restrict__ cntC,
                                               const int* __restrict__ cntV, int nbC,
                                               const int* __restrict__ bsumC,
                                               const int* __restrict__ bsumV,
                                               int* __restrict__ rowC, int* __restrict__ rowV) {
    int b = blockIdx.x, t = threadIdx.x;
    const int* cnt; int N; const int* bs; int* row; int bb;
    if (b < nbC) { cnt = cntC; N = C_N; bs = bsumC; row = rowC; bb = b; }
    else         { cnt = cntV; N = V_N; bs = bsumV; row = rowV; bb = b - nbC; }
    int base = bb * 1024 + t * 4;
    int v[4], local[4];
    #pragma unroll
    for (int q = 0; q < 4; ++q) { int i = base + q; v[q] = (i < N) ? cnt[i] : 0; }
    local[0] = 0; local[1] = v[0]; local[2] = v[0] + v[1]; local[3] = v[0] + v[1] + v[2];
    int mysum = local[3] + v[3];
    __shared__ int sh[256];
    sh[t] = mysum; __syncthreads();
    for (int d = 1; d < 256; d <<= 1) {
        int add = (t >= d) ? sh[t - d] : 0;
        __syncthreads();
        sh[t] += add;
        __syncthreads();
    }
    int excl = sh[t] - mysum + bs[bb];
    #pragma unroll
    for (int q = 0; q < 4; ++q) {
        int i = base + q;
        if (i < N) row[i] = excl + local[q];
    }
}

// ---------------------------------------------------------------------------
// Layer-0 attention logits from cf0 + per-block max partials.  Also zeroes
// the per-layer Sg accumulators (consumed later in stream order).
// ---------------------------------------------------------------------------
__global__ __launch_bounds__(256) void k_att0(const float* __restrict__ cf,
                                              const float* __restrict__ aw1,
                                              const float* __restrict__ ab1,
                                              const float* __restrict__ aw2,
                                              const float* __restrict__ ab2,
                                              float* __restrict__ logits,
                                              float* __restrict__ pmax,
                                              float* __restrict__ Sg) {
    if (blockIdx.x == 0 && threadIdx.x < 8) Sg[threadIdx.x] = 0.0f;
    int c = blockIdx.x * blockDim.x + threadIdx.x;
    float logit = -1e30f;
    if (c < C_N) {
        float h0 = cf[c * 3], h1 = cf[c * 3 + 1], h2 = cf[c * 3 + 2];
        float acc = ab2[0];
        #pragma unroll
        for (int k = 0; k < 64; ++k) {
            float tv = ftanh(aw1[k * 3] * h0 + aw1[k * 3 + 1] * h1 +
                             aw1[k * 3 + 2] * h2 + ab1[k]);
            acc += aw2[k] * tv;
        }
        logits[c] = acc;
        logit = acc;
    }
    float m = logit;
    #pragma unroll
    for (int off = 32; off; off >>= 1) m = fmaxf(m, __shfl_xor(m, off));
    __shared__ float smax[4];
    int lane = threadIdx.x & 63, wid = threadIdx.x >> 6;
    if (lane == 0) smax[wid] = m;
    __syncthreads();
    if (threadIdx.x == 0)
        pmax[blockIdx.x] = fmaxf(fmaxf(smax[0], smax[1]), fmaxf(smax[2], smax[3]));
}

// ---------------------------------------------------------------------------
// Merged edge kernel: one thread per edge computes BOTH direction messages
// (v2c from vf, c2v from cf) and scatters fp16 into CSR slots.  First NCBLK
// blocks additionally compute the softmax exp-partials for this layer
// (independent of the edge work; Sg consumed only by k_nodeM).
// ---------------------------------------------------------------------------
__global__ __launch_bounds__(256) void k_edgeM(const float* __restrict__ vf,
                                               const float* __restrict__ cf,
                                               const float* __restrict__ ef,
                                               const int* __restrict__ var_idx,
                                               const int* __restrict__ cls_idx,
                                               const int* __restrict__ rowC,
                                               const int* __restrict__ rowV,
                                               const int* __restrict__ rankC,
                                               const int* __restrict__ rankV,
                                               const float* __restrict__ prepA,
                                               const float* __restrict__ prepB,
                                               const float* __restrict__ logits,
                                               const float* __restrict__ pmax,
                                               float* __restrict__ SgL,
                                               uint2* __restrict__ umsgC,
                                               uint2* __restrict__ umsgV) {
    __shared__ float WA[1040], WB[1040];
    for (int i = threadIdx.x; i < 1040; i += 256) { WA[i] = prepA[i]; WB[i] = prepB[i]; }
    __syncthreads();
    int e = blockIdx.x * 256 + threadIdx.x;
    if (e < E_N) {
        int v = var_idx[e], c = cls_idx[e];
        float2 efv = *(const float2*)(ef + 2 * (size_t)e);
        float a0 = vf[v * 3], a1 = vf[v * 3 + 1], a2 = vf[v * 3 + 2];
        float b0 = cf[c * 3], b1 = cf[c * 3 + 1], b2 = cf[c * 3 + 2];
        float uC[9], uV[9];
        #pragma unroll
        for (int k = 0; k < 9; ++k) { uC[k] = 0.0f; uV[k] = 0.0f; }
        for (int j = 0; j < 64; ++j) {
            const float* wj = &WA[j * 16];
            float h = fmaxf(wj[0] * a0 + wj[1] * a1 + wj[2] * a2 +
                            wj[3] * efv.x + wj[4] * efv.y + wj[5], 0.0f);
            const float* qj = &WB[j * 16];
            float g = fmaxf(qj[0] * b0 + qj[1] * b1 + qj[2] * b2 +
                            qj[3] * efv.x + qj[4] * efv.y + qj[5], 0.0f);
            #pragma unroll
            for (int k = 0; k < 9; ++k) { uC[k] += wj[6 + k] * h; uV[k] += qj[6 + k] * g; }
        }
        union { __half h[12]; uint2 q[3]; } pk;
        #pragma unroll
        for (int k = 0; k < 9; ++k) pk.h[k] = __float2half(uC[k]);
        pk.h[9] = pk.h[10] = pk.h[11] = __float2half(0.0f);
        size_t pC = (size_t)(rowC[c] + rankC[e]) * 3;
        umsgC[pC] = pk.q[0]; umsgC[pC + 1] = pk.q[1]; umsgC[pC + 2] = pk.q[2];
        #pragma unroll
        for (int k = 0; k < 9; ++k) pk.h[k] = __float2half(uV[k]);
        size_t pV = (size_t)(rowV[v] + rankV[e]) * 3;
        umsgV[pV] = pk.q[0]; umsgV[pV + 1] = pk.q[1]; umsgV[pV + 2] = pk.q[2];
    }
    // -------- fused softmax partial (this layer's Sg) --------
    if (blockIdx.x < NCBLK) {
        __shared__ float sh[4];
        float m = -1e30f;
        for (int i = threadIdx.x; i < NCBLK; i += 256) m = fmaxf(m, pmax[i]);
        #pragma unroll
        for (int off = 32; off; off >>= 1) m = fmaxf(m, __shfl_xor(m, off));
        int lane = threadIdx.x & 63, wid = threadIdx.x >> 6;
        if (lane == 0) sh[wid] = m;
        __syncthreads();
        float mm = fmaxf(fmaxf(sh[0], sh[1]), fmaxf(sh[2], sh[3]));
        __syncthreads();
        int c = blockIdx.x * 256 + threadIdx.x;
        float ex = (c < C_N) ? __expf(logits[c] - mm) : 0.0f;
        #pragma unroll
        for (int off = 32; off; off >>= 1) ex += __shfl_xor(ex, off);
        if (lane == 0) sh[wid] = ex;
        __syncthreads();
        if (threadIdx.x == 0) {
            unsafeAtomicAdd(&SgL[0], sh[0] + sh[1] + sh[2] + sh[3]);
            if (blockIdx.x == 0) SgL[1] = mm;
        }
    }
}

// ---------------------------------------------------------------------------
// Merged node kernel: blocks [0,NCBLK) = clauses (gather + att-scale + GRU +
// next-layer attention logits from the fresh h'), blocks [NCBLK,..) = vars
// (gather + GRU).  In-place safe (thread-local read->write).
// ---------------------------------------------------------------------------
__global__ __launch_bounds__(256) void k_nodeM(const uint2* __restrict__ umsgC,
                                               const uint2* __restrict__ umsgV,
                                               const int* __restrict__ rowC,
                                               const int* __restrict__ rowV,
                                               const float* __restrict__ cfin,
                                               const float* __restrict__ vfin,
                                               float* __restrict__ cfout,
                                               float* __restrict__ vfout,
                                               const float* __restrict__ SgL,
                                               float* __restrict__ logits,
                                               float* __restrict__ pmax,
                                               const float* __restrict__ c2C,
                                               const float* __restrict__ c2V,
                                               const float* __restrict__ cls_whh,
                                               const float* __restrict__ cls_bih,
                                               const float* __restrict__ cls_bhh,
                                               const float* __restrict__ var_whh,
                                               const float* __restrict__ var_bih,
                                               const float* __restrict__ var_bhh,
                                               const float* __restrict__ aw1,
                                               const float* __restrict__ ab1,
                                               const float* __restrict__ aw2,
                                               const float* __restrict__ ab2,
                                               int do_att) {
    int b = blockIdx.x;
    if (b < NCBLK) {
        int i = b * 256 + threadIdx.x;
        float logit = -1e30f;
        if (i < C_N) {
            int p0 = rowC[i], p1 = rowC[i + 1];
            float u[9];
            #pragma unroll
            for (int k = 0; k < 9; ++k) u[k] = 0.0f;
            for (int p = p0; p < p1; ++p) {
                union { __half h[12]; uint2 q[3]; } pk;
                const uint2* r = umsgC + (size_t)p * 3;
                pk.q[0] = r[0]; pk.q[1] = r[1]; pk.q[2] = r[2];
                #pragma unroll
                for (int k = 0; k < 9; ++k) u[k] += __half2float(pk.h[k]);
            }
            float cnt = (float)(p1 - p0);
            float scale = __expf(logits[i] - SgL[1]) / SgL[0];
            float h0 = cfin[i * 3], h1 = cfin[i * 3 + 1], h2 = cfin[i * 3 + 2];
            float gi[9], gh[9];
            #pragma unroll
            for (int k = 0; k < 9; ++k) gi[k] = scale * (u[k] + cnt * c2C[k]) + cls_bih[k];
            #pragma unroll
            for (int k = 0; k < 9; ++k)
                gh[k] = cls_whh[k * 3] * h0 + cls_whh[k * 3 + 1] * h1 + cls_whh[k * 3 + 2] * h2 + cls_bhh[k];
            float r0 = fsig(gi[0] + gh[0]), r1 = fsig(gi[1] + gh[1]), r2 = fsig(gi[2] + gh[2]);
            float z0 = fsig(gi[3] + gh[3]), z1 = fsig(gi[4] + gh[4]), z2 = fsig(gi[5] + gh[5]);
            float n0 = ftanh(gi[6] + r0 * gh[6]);
            float n1 = ftanh(gi[7] + r1 * gh[7]);
            float n2 = ftanh(gi[8] + r2 * gh[8]);
            float o0 = (1.0f - z0) * n0 + z0 * h0;
            float o1 = (1.0f - z1) * n1 + z1 * h1;
            float o2 = (1.0f - z2) * n2 + z2 * h2;
            cfout[i * 3 + 0] = o0;
            cfout[i * 3 + 1] = o1;
            cfout[i * 3 + 2] = o2;
            if (do_att) {
                float acc = ab2[0];
                #pragma unroll
                for (int k = 0; k < 64; ++k) {
                    float tv = ftanh(aw1[k * 3] * o0 + aw1[k * 3 + 1] * o1 +
                                     aw1[k * 3 + 2] * o2 + ab1[k]);
                    acc += aw2[k] * tv;
                }
                logits[i] = acc;
                logit = acc;
            }
        }
        if (do_att) {
            float m = logit;
            #pragma unroll
            for (int off = 32; off; off >>= 1) m = fmaxf(m, __shfl_xor(m, off));
            __shared__ float smax[4];
            int lane = threadIdx.x & 63, wid = threadIdx.x >> 6;
            if (lane == 0) smax[wid] = m;
            __syncthreads();
            if (threadIdx.x == 0)
                pmax[b] = fmaxf(fmaxf(smax[0], smax[1]), fmaxf(smax[2], smax[3]));
        }
    } else {
        int i = (b - NCBLK) * 256 + threadIdx.x;
        if (i >= V_N) return;
        int p0 = rowV[i], p1 = rowV[i + 1];
        float u[9];
        #pragma unroll
        for (int k = 0; k < 9; ++k) u[k] = 0.0f;
        for (int p = p0; p < p1; ++p) {
            union { __half h[12]; uint2 q[3]; } pk;
            const uint2* r = umsgV + (size_t)p * 3;
            pk.q[0] = r[0]; pk.q[1] = r[1]; pk.q[2] = r[2];
            #pragma unroll
            for (int k = 0; k < 9; ++k) u[k] += __half2float(pk.h[k]);
        }
        float cnt = (float)(p1 - p0);
        float h0 = vfin[i * 3], h1 = vfin[i * 3 + 1], h2 = vfin[i * 3 + 2];
        float gi[9], gh[9];
        #pragma unroll
        for (int k = 0; k < 9; ++k) gi[k] = u[k] + cnt * c2V[k] + var_bih[k];
        #pragma unroll
        for (int k = 0; k < 9; ++k)
            gh[k] = var_whh[k * 3] * h0 + var_whh[k * 3 + 1] * h1 + var_whh[k * 3 + 2] * h2 + var_bhh[k];
        float r0 = fsig(gi[0] + gh[0]), r1 = fsig(gi[1] + gh[1]), r2 = fsig(gi[2] + gh[2]);
        float z0 = fsig(gi[3] + gh[3]), z1 = fsig(gi[4] + gh[4]), z2 = fsig(gi[5] + gh[5]);
        float n0 = ftanh(gi[6] + r0 * gh[6]);
        float n1 = ftanh(gi[7] + r1 * gh[7]);
        float n2 = ftanh(gi[8] + r2 * gh[8]);
        vfout[i * 3 + 0] = (1.0f - z0) * n0 + z0 * h0;
        vfout[i * 3 + 1] = (1.0f - z1) * n1 + z1 * h1;
        vfout[i * 3 + 2] = (1.0f - z2) * n2 + z2 * h2;
    }
}

extern "C" void kernel_launch(void* const* d_in, const int* in_sizes, int n_in,
                              void* d_out, int out_size, void* d_ws, size_t ws_size,
                              hipStream_t stream) {
    const float* vf0     = (const float*)d_in[0];
    const float* cf0     = (const float*)d_in[1];
    const float* ef      = (const float*)d_in[2];
    const float* v2c_w1  = (const float*)d_in[3];
    const float* v2c_b1  = (const float*)d_in[4];
    const float* v2c_w2  = (const float*)d_in[5];
    const float* v2c_b2  = (const float*)d_in[6];
    const float* c2v_w1  = (const float*)d_in[7];
    const float* c2v_b1  = (const float*)d_in[8];
    const float* c2v_w2  = (const float*)d_in[9];
    const float* c2v_b2  = (const float*)d_in[10];
    const float* var_wih = (const float*)d_in[11];
    const float* var_whh = (const float*)d_in[12];
    const float* var_bih = (const float*)d_in[13];
    const float* var_bhh = (const float*)d_in[14];
    const float* cls_wih = (const float*)d_in[15];
    const float* cls_whh = (const float*)d_in[16];
    const float* cls_bih = (const float*)d_in[17];
    const float* cls_bhh = (const float*)d_in[18];
    const float* att_w1  = (const float*)d_in[19];
    const float* att_b1  = (const float*)d_in[20];
    const float* att_w2  = (const float*)d_in[21];
    const float* att_b2  = (const float*)d_in[22];
    const int*   var_idx = (const int*)d_in[23];
    const int*   cls_idx = (const int*)d_in[24];
    float* dout = (float*)d_out;

    // ---- workspace layout ----
    char* w = (char*)d_ws;
    auto alloc = [&](size_t bytes) { char* p = w; w += (bytes + 255) & ~(size_t)255; return p; };
    int*   rowC   = (int*)alloc((C_N + 1) * 4);
    int*   rowV   = (int*)alloc((V_N + 1) * 4);
    int*   cntC   = (int*)alloc((size_t)C_N * 4);   // cntC/cntV adjacent: single memset
    int*   cntV   = (int*)alloc((size_t)V_N * 4);
    char*  cntEnd = w;
    int*   rankC  = (int*)alloc((size_t)E_N * 4);
    int*   rankV  = (int*)alloc((size_t)E_N * 4);
    int*   bsumC  = (int*)alloc(512 * 4);
    int*   bsumV  = (int*)alloc(512 * 4);
    float* logits = (float*)alloc((size_t)C_N * 4);
    float* pmax   = (float*)alloc(2048 * 4);
    float* Sg     = (float*)alloc(64 * 4);          // per-layer: Sg[2l]=S, Sg[2l+1]=gmax
    float* prep   = (float*)alloc(6 * 1040 * 4);
    uint2* umsgC  = (uint2*)alloc((size_t)E_N * 3 * 8);
    uint2* umsgV  = (uint2*)alloc((size_t)E_N * 3 * 8);
    float* vfW    = (float*)alloc((size_t)V_N * 3 * 4);
    float* cfW    = (float*)alloc((size_t)C_N * 3 * 4);

    const int nbC = (C_N + 1023) / 1024;   // 411
    const int nbV = (V_N + 1023) / 1024;   // 98

    k_prep<<<(6 * 1040 + 255) / 256, 256, 0, stream>>>(
        v2c_w1, v2c_b1, v2c_w2, v2c_b2, c2v_w1, c2v_b1, c2v_w2, c2v_b2,
        cls_wih, var_wih, prep);

    hipMemsetAsync(cntC, 0, (size_t)(cntEnd - (char*)cntC), stream);
    k_countrank<<<NEBLK, 256, 0, stream>>>(cls_idx, var_idx, cntC, cntV, rankC, rankV);
    k_scanA<<<nbC + nbV, 256, 0, stream>>>(cntC, cntV, nbC, bsumC, bsumV);
    k_scanB<<<2, 512, 0, stream>>>(bsumC, nbC, rowC + C_N, bsumV, nbV, rowV + V_N);
    k_scanC<<<nbC + nbV, 256, 0, stream>>>(cntC, cntV, nbC, bsumC, bsumV, rowC, rowV);

    k_att0<<<NCBLK, 256, 0, stream>>>(cf0, att_w1, att_b1, att_w2, att_b2,
                                      logits, pmax, Sg);

    for (int l = 0; l < L_N; ++l) {
        const float* vin = (l == 0) ? vf0 : vfW;
        const float* cin = (l == 0) ? cf0 : cfW;
        float* vout = (l == 2) ? dout : vfW;
        float* cout = (l == 2) ? (dout + (size_t)V_N * 3) : cfW;
        const float* prepA = prep + l * 1040;          // v2c (side 0)
        const float* prepB = prep + (3 + l) * 1040;    // c2v (side 1)
        int la = (l < 2) ? (l + 1) : 2;                // att weights for next layer

        k_edgeM<<<NEBLK, 256, 0, stream>>>(vin, cin, ef, var_idx, cls_idx,
                                           rowC, rowV, rankC, rankV,
                                           prepA, prepB, logits, pmax,
                                           Sg + 2 * l, umsgC, umsgV);

        k_nodeM<<<NCBLK + NVBLK, 256, 0, stream>>>(umsgC, umsgV, rowC, rowV,
                                                   cin, vin, cout, vout,
                                                   Sg + 2 * l, logits, pmax,
                                                   prepA + 1024, prepB + 1024,
                                                   cls_whh + l * 27, cls_bih + l * 9, cls_bhh + l * 9,
                                                   var_whh + l * 27, var_bih + l * 9, var_bhh + l * 9,
                                                   att_w1 + la * 192, att_b1 + la * 64,
                                                   att_w2 + la * 64, att_b2 + la,
                                                   (l < 2) ? 1 : 0);
    }
}